// Round 12
// baseline (209.658 us; speedup 1.0000x reference)
//
#include <hip/hip_runtime.h>
#include <stdint.h>

// BasicAttention: B=4, C=256, IC=128, N=4096, fp32 in/out.
// R19: both loads off attn's critical path at NET-ZERO register cost.
// R18 established: attn latency/ILP-bound (L2 at 48% of XCD ceiling, 2
// waves/SIMD reg-capped, ~2400cy/iter/wave idle on K-JIT->QK->exp->PV chain).
// Swap: vA (32 VGPR) -> per-wave LDS double-buffer via glds16 issued at iter
// end 1-ahead (zero VGPR); freed 32 regs -> K register double-buffer, K[t+1]
// issued after QK-t2. Load-reg bucket unchanged: kv64+vB32 = 96 = old
// kv32+vA32+vB32 (R13's spill was +64 net; this is +-0 -> VGPR stays ~128).
// vmcnt chains (R11/R12-verified mechanism), issue order vB[t] -> K[t+1] ->
// glds vA[t+1]: QK[t+1] waits vmcnt(8) (glds in flight), PV[t] waits vmcnt(8)
// (K[t+1] in flight, retires glds vA[t]) -- no drain, no fences, NO setprio
// (R17/R18: setprio = spill trigger at 256-reg saturation). R18 rotation kept.
// LDS: vst[4][2][8192] unioned with epilogue obuf = 64KB, 2 blocks/CU.
// proj/cvt = R14 exact. Micros: exp2-fold, permlane32_swap, in-place exp.
// Primary check: WRITE_SIZE==16384 && VGPR~128 (spill => revert to vA-LDS only).
// ws: qF 2MB | kF 2MB | vF 4MB | wbf(bf16) 256KB.

#define Bn 4
#define Cn 256
#define ICn 128
#define Nn 4096

typedef __attribute__((ext_vector_type(8))) short bf16x8;
typedef __attribute__((ext_vector_type(4))) float f32x4;
typedef __attribute__((ext_vector_type(16))) float f32x16;
typedef __attribute__((ext_vector_type(8))) int i32x8;

#define SCALE1 0x7f7f7f7f  // e8m0 127 (=2^0) in all 4 bytes: scale = 1.0

__device__ __forceinline__ unsigned short f2bf(float f) {
  union { float f; uint32_t u; } v; v.f = f;
  uint32_t r = (v.u + 0x7fffu + ((v.u >> 16) & 1u)) >> 16;
  return (unsigned short)r;
}

__device__ __forceinline__ uint32_t pk4_fp8(float a, float b, float c, float d) {
  int r = 0;
  r = __builtin_amdgcn_cvt_pk_fp8_f32(a, b, r, false);
  r = __builtin_amdgcn_cvt_pk_fp8_f32(c, d, r, true);
  return (uint32_t)r;
}

// async global->LDS, 16B/lane; lds dest = wave-uniform base + lane*16,
// global src is per-lane.
__device__ __forceinline__ void glds16(const uint8_t* g, uint8_t* l) {
  __builtin_amdgcn_global_load_lds((const __attribute__((address_space(1))) void*)g,
                                   (__attribute__((address_space(3))) void*)l, 16, 0, 0);
}

// wbf frag-major (bf16): [tile(32)][kk(8)][lane(64)][j(8)]; tiles 0-7 Wq, 8-15 Wk, 16-31 Wv.
__global__ __launch_bounds__(256) void cvt_weights(const float* __restrict__ Wq,
                                                   const float* __restrict__ Wk,
                                                   const float* __restrict__ Wv,
                                                   unsigned short* __restrict__ wbf) {
  int t = blockIdx.x * 256 + threadIdx.x;   // 0..16383 = tile*512 + kk*64 + lane
  int tile = t >> 9;
  int kk = (t >> 6) & 7;
  int lane = t & 63;
  const float* W; int row;
  if (tile < 8)       { W = Wq; row = tile * 16 + (lane & 15); }
  else if (tile < 16) { W = Wk; row = (tile - 8) * 16 + (lane & 15); }
  else                { W = Wv; row = (tile - 16) * 16 + (lane & 15); }
  const float* src = W + (size_t)row * Cn + kk * 32 + (lane >> 4) * 8;
  float4 f0 = *(const float4*)src;
  float4 f1 = *(const float4*)(src + 4);
  ushort4 o0, o1;
  o0.x = f2bf(f0.x); o0.y = f2bf(f0.y); o0.z = f2bf(f0.z); o0.w = f2bf(f0.w);
  o1.x = f2bf(f1.x); o1.y = f2bf(f1.y); o1.z = f2bf(f1.z); o1.w = f2bf(f1.w);
  *(ushort4*)(wbf + (size_t)t * 8)     = o0;
  *(ushort4*)(wbf + (size_t)t * 8 + 4) = o1;
}

// qF/kF fp8 x64-frag layout: [b][nt(128)][mf(2)][lane(64)][32B]; lane = l5*32+px31,
//   dword d at mf covers ic = mf*64 + l5*32 + d*4 .. +3 for pixel px.
// vF fp8 x64-frag layout: [b][kb64(64)][ct(8)][lane(64)][32B]; lane = l5*32+ch31,
//   dword d covers keys = l5*32 + d*4 .. +3 (within the 64-key block) for ch.
// wave0: q, wave1: k, waves 2-3: v (8 vtg each).
__global__ __launch_bounds__(256, 2) void proj_kernel(const float* __restrict__ x,
                                                      const unsigned short* __restrict__ wbf,
                                                      const float* __restrict__ bq,
                                                      const float* __restrict__ bk,
                                                      const float* __restrict__ bv,
                                                      uint8_t* __restrict__ qF,
                                                      uint8_t* __restrict__ kF,
                                                      uint8_t* __restrict__ vF) {
  const int b = blockIdx.y;
  const int ntile = blockIdx.x;            // 32-pixel tile
  const int px0 = ntile * 32;
  const int tid = threadIdx.x;
  const int lane = tid & 63;
  const int w = tid >> 6;
  const int c0 = lane & 15, g = lane >> 4;
  // 128^-0.25 * sqrt(log2(e)), folded into BOTH q and k: S comes out in log2
  // domain so attn softmax is a bare v_exp_f32 (2^x).
  const float hscale = 0.3570958292f;

  __shared__ __align__(16) unsigned short xT[32][264];  // [px][c] (16.9 KB)
  __shared__ __align__(16) uint8_t tb[4][4096];         // per-wave store-staging (16 KB)

  #pragma unroll
  for (int t = 0; t < 8; ++t) {            // 8 c-rows x 128B contiguous per wave-instr
    int c = (tid >> 3) + t * 32;
    int i8 = tid & 7;
    float4 f4 = *(const float4*)(x + ((size_t)(b * Cn + c)) * Nn + px0 + i8 * 4);
    xT[i8 * 4 + 0][c] = f2bf(f4.x);
    xT[i8 * 4 + 1][c] = f2bf(f4.y);
    xT[i8 * 4 + 2][c] = f2bf(f4.z);
    xT[i8 * 4 + 3][c] = f2bf(f4.w);
  }
  __syncthreads();

  bf16x8 a[2][8];   // x frags for both 16-px halves
  #pragma unroll
  for (int h = 0; h < 2; ++h)
    #pragma unroll
    for (int kk = 0; kk < 8; ++kk)
      a[h][kk] = *(const bf16x8*)&xT[h * 16 + c0][kk * 32 + g * 8];

  f32x4 zero = {0.f, 0.f, 0.f, 0.f};
  uint8_t* tw = &tb[w][0];

  if (w < 2) {
    // wave0: q (wbf tiles 0-7), wave1: k (tiles 8-15). A = W (m=ic), B = x^T (n=px).
    const int isq = (w == 0);
    const float* bias = isq ? bq : bk;
    uint8_t* dst = isq ? qF : kF;
    #pragma unroll
    for (int otl = 0; otl < 8; ++otl) {
      const int wt = (isq ? 0 : 8) + otl;
      bf16x8 wf[8];
      #pragma unroll
      for (int kk = 0; kk < 8; ++kk)
        wf[kk] = *(const bf16x8*)(wbf + (((size_t)wt * 8 + kk) << 9) + lane * 8);
      float4 bz = *(const float4*)(bias + otl * 16 + g * 4);
      #pragma unroll
      for (int h = 0; h < 2; ++h) {
        f32x4 acc = zero;
        #pragma unroll
        for (int kk = 0; kk < 8; ++kk)
          acc = __builtin_amdgcn_mfma_f32_16x16x32_bf16(wf[kk], a[h][kk], acc, 0, 0, 0);
        // D: row = ic = otl*16 + g*4 + r, col = px = h*16 + c0
        uint32_t d = pk4_fp8((acc[0] + bz.x) * hscale, (acc[1] + bz.y) * hscale,
                             (acc[2] + bz.z) * hscale, (acc[3] + bz.w) * hscale);
        // dword D = ic/4 = otl*4+g in [0,32): mf = D>>4, l5 = (D>>3)&1, d = D&7
        int D = otl * 4 + g;
        int off = ((D >> 4) << 11) + (((((D >> 3) & 1) << 5) + h * 16 + c0) << 5) + ((D & 7) << 2);
        *(uint32_t*)(tw + off) = d;            // ds_write_b32 (cheap scatter)
      }
    }
    // coalesced store-back: flat LDS layout == flat global frag layout
    size_t base = ((size_t)(b * 128 + ntile)) << 12;   // 4096B per (b,ntile)
    #pragma unroll
    for (int r = 0; r < 4; ++r) {
      uint4 v = *(const uint4*)(tw + r * 1024 + lane * 16);
      *(uint4*)(dst + base + r * 1024 + lane * 16) = v;
    }
  } else {
    // waves 2,3: v tiles. A = x (m=px), B = W^T (n=ch).
    #pragma unroll
    for (int oi = 0; oi < 8; ++oi) {
      const int vtg = (w - 2) * 8 + oi;
      bf16x8 wf[8];
      #pragma unroll
      for (int kk = 0; kk < 8; ++kk)
        wf[kk] = *(const bf16x8*)(wbf + (((size_t)(16 + vtg) * 8 + kk) << 9) + lane * 8);
      const float bias = bv[vtg * 16 + c0];
      #pragma unroll
      for (int h = 0; h < 2; ++h) {
        f32x4 acc = zero;
        #pragma unroll
        for (int kk = 0; kk < 8; ++kk)
          acc = __builtin_amdgcn_mfma_f32_16x16x32_bf16(a[h][kk], wf[kk], acc, 0, 0, 0);
        // D: row = key = px0 + h*16 + g*4 + r, col = ch = vtg*16 + c0
        uint32_t d = pk4_fp8(acc[0] + bias, acc[1] + bias, acc[2] + bias, acc[3] + bias);
        // tb: [ct_local(4)][ch31(32)][32B], dword = h*4+g
        int off = (((vtg >> 1) & 3) << 10) + ((((vtg & 1) << 4) + c0) << 5) + ((h * 4 + g) << 2);
        *(uint32_t*)(tw + off) = d;            // ds_write_b32
      }
    }
    // coalesced store-back: 2 rounds x (two 1KB segments per wave-instr)
    const int ctb = (w - 2) * 4;
    size_t base0 = (((size_t)(b * 64 + (ntile >> 1)) * 8 + ctb) << 11)
                 + (size_t)(((ntile & 1) << 5) << 5);      // lane-half select
    #pragma unroll
    for (int r = 0; r < 2; ++r) {
      int ctl = r * 2 + (lane >> 5);
      int li = lane & 31;
      const uint8_t* s = tw + r * 2048 + lane * 32;
      uint4 v0 = *(const uint4*)(s);
      uint4 v1 = *(const uint4*)(s + 16);
      uint8_t* gp = vF + base0 + ((size_t)ctl << 11) + li * 32;
      *(uint4*)(gp) = v0;
      *(uint4*)(gp + 16) = v1;
    }
  }
}

// One attn iteration. P = it&1 (kv buffer + vst buffer parity), PRE = prefetch
// K[t+1] + glds vA[t+1] (false only for it=15).
// Issue order per iter: vB[t] -> K[t+1] -> (PV) -> glds vA[t+1]; in-order vmcnt
// gives QK[t+1] wait = vmcnt(8) (glds outstanding), PV[t] wait = vmcnt(8)
// (K[t+1] outstanding, retires glds vA[t] issued last iter). No drains.
template <int P, bool PRE>
__device__ __forceinline__ void attn_body(int it, int ks, int ph, int L,
                                          const uint8_t* kBase, const uint8_t* vGsrc,
                                          uint8_t* vst_w, const i32x8 (&qv)[2],
                                          i32x8 (&kv0)[4], i32x8 (&kv1)[4],
                                          f32x16 (&oacc)[8], float& lacc) {
  i32x8 (&kvP)[4] = P ? kv1 : kv0;
  i32x8 (&kvN)[4] = P ? kv0 : kv1;
  const int kb = ks * 16 + ((it + ph) & 15);
  const int kbn = ks * 16 + ((it + 1 + ph) & 15);
  const uint8_t* vp = vGsrc + (size_t)kb * 16384;

  // (1) QK tile1 (keys 0-31). S^T: col=l31=qrow, row(reg i)=(i&3)+8*(i>>2)+4*l5.
  f32x16 s;
  #pragma unroll
  for (int i = 0; i < 16; ++i) s[i] = 0.f;
  s = __builtin_amdgcn_mfma_scale_f32_32x32x64_f8f6f4(kvP[0], qv[0], s, 0, 0, 0, SCALE1, 0, SCALE1);
  s = __builtin_amdgcn_mfma_scale_f32_32x32x64_f8f6f4(kvP[1], qv[1], s, 0, 0, 0, SCALE1, 0, SCALE1);
  // exp/pack tile1 (one S tile live at a time)
  #pragma unroll
  for (int i = 0; i < 16; ++i) {
    float r;
    asm("v_exp_f32 %0, %1" : "=v"(r) : "v"(s[i]));
    s[i] = r;
  }
  #pragma unroll
  for (int i = 0; i < 16; ++i) lacc += s[i];
  uint32_t d0 = pk4_fp8(s[0], s[1], s[2], s[3]);
  uint32_t d1 = pk4_fp8(s[4], s[5], s[6], s[7]);
  uint32_t d2 = pk4_fp8(s[8], s[9], s[10], s[11]);
  uint32_t d3 = pk4_fp8(s[12], s[13], s[14], s[15]);

  // (2) QK tile2 (keys 32-63), s reused
  #pragma unroll
  for (int i = 0; i < 16; ++i) s[i] = 0.f;
  s = __builtin_amdgcn_mfma_scale_f32_32x32x64_f8f6f4(kvP[2], qv[0], s, 0, 0, 0, SCALE1, 0, SCALE1);
  s = __builtin_amdgcn_mfma_scale_f32_32x32x64_f8f6f4(kvP[3], qv[1], s, 0, 0, 0, SCALE1, 0, SCALE1);

  // (3) vB[t] register loads -- issued BEFORE K[t+1] so PV's wait keeps K[t+1]
  //     in flight (in-order retirement).
  uint4 vB[8];
  #pragma unroll
  for (int ct = 0; ct < 8; ++ct) vB[ct] = *(const uint4*)(vp + ct * 2048 + 16);

  // (4) K[t+1] -> kvN (freed-by-vA registers; consumed top of next iter)
  if constexpr (PRE) {
    const uint8_t* kp = kBase + (size_t)kbn * 8192;
    #pragma unroll
    for (int f = 0; f < 4; ++f) {
      union { uint4 u[2]; i32x8 v; } u;
      u.u[0] = *(const uint4*)(kp + f * 2048);
      u.u[1] = *(const uint4*)(kp + f * 2048 + 16);
      kvN[f] = u.v;
    }
  }

  // (5) exp/pack tile2 + P^T assembly (4 permlane32_swap, selection-free)
  #pragma unroll
  for (int i = 0; i < 16; ++i) {
    float r;
    asm("v_exp_f32 %0, %1" : "=v"(r) : "v"(s[i]));
    s[i] = r;
  }
  #pragma unroll
  for (int i = 0; i < 16; ++i) lacc += s[i];
  uint32_t e0 = pk4_fp8(s[0], s[1], s[2], s[3]);
  uint32_t e1 = pk4_fp8(s[4], s[5], s[6], s[7]);
  uint32_t e2 = pk4_fp8(s[8], s[9], s[10], s[11]);
  uint32_t e3 = pk4_fp8(s[12], s[13], s[14], s[15]);

  union { uint32_t w[8]; i32x8 v; } pf;
  {
    uint32_t a0 = e0, b0 = d0;
    asm("v_permlane32_swap_b32 %0, %1" : "+v"(a0), "+v"(b0));
    pf.w[0] = b0; pf.w[1] = a0;
    uint32_t a1 = e1, b1 = d1;
    asm("v_permlane32_swap_b32 %0, %1" : "+v"(a1), "+v"(b1));
    pf.w[2] = b1; pf.w[3] = a1;
    uint32_t a2 = e2, b2 = d2;
    asm("v_permlane32_swap_b32 %0, %1" : "+v"(a2), "+v"(b2));
    pf.w[4] = b2; pf.w[5] = a2;
    uint32_t a3 = e3, b3 = d3;
    asm("v_permlane32_swap_b32 %0, %1" : "+v"(a3), "+v"(b3));
    pf.w[6] = b3; pf.w[7] = a3;
  }

  // (6) PV: vA from LDS (glds'ed last iter; retired by this iter's waits) +
  //     vB regs. D layout unchanged -> epilogue unchanged.
  #pragma unroll
  for (int ct = 0; ct < 8; ++ct) {
    union { uint4 u[2]; i32x8 v; } va;
    va.u[0] = *(const uint4*)(vst_w + P * 8192 + ct * 1024 + (size_t)L * 16);
    va.u[1] = vB[ct];
    oacc[ct] = __builtin_amdgcn_mfma_scale_f32_32x32x64_f8f6f4(va.v, pf.v, oacc[ct], 0, 0, 0, SCALE1, 0, SCALE1);
  }

  // (7) glds vA[t+1] -> vst[P^1] (async, zero VGPR; a full QK+exp to land)
  if constexpr (PRE) {
    const uint8_t* vpn = vGsrc + (size_t)kbn * 16384;
    uint8_t* ldst = vst_w + (P ^ 1) * 8192;
    #pragma unroll
    for (int ct = 0; ct < 8; ++ct)
      glds16(vpn + ct * 2048, ldst + ct * 1024);
  }
}

// attn: 512 blocks x 256 thr (4 waves = 4 key-quarters), 32 q-rows/block,
// 16 iters x 64 keys, all-MX x64 MFMAs. K reg-dbuf + vA LDS-dbuf, rotation.
__global__ __launch_bounds__(256, 2) void attn_kernel(const uint8_t* __restrict__ qF,
                                                      const uint8_t* __restrict__ kF,
                                                      const uint8_t* __restrict__ vF,
                                                      const float* __restrict__ x,
                                                      const float* __restrict__ gamma,
                                                      float* __restrict__ out) {
  const int blk = blockIdx.x;
  const int b = (blk & 7) >> 1;                     // 2 XCDs/batch: q+k+v 2MB < 4MB L2
  const int rg = (blk >> 3) | ((blk & 1) << 6);     // 0..127
  const int n0 = rg * 32;
  const int ph = (blk >> 3) & 15;                   // key-loop phase (R18: -1.7us)
  const int tid = threadIdx.x;
  const int L = tid & 63;
  const int ks = tid >> 6;                          // key quarter
  const int l31 = L & 31, l5 = L >> 5;
  const bool lo = (l5 == 0);

  __shared__ __align__(16) union SM {
    uint8_t vst[4][2][8192];                        // per-wave vA double-buffer (64 KB)
    struct { float obuf[256][33]; float lsum[4][32]; } e;   // epilogue overlay
  } sm;

  // Q B-frags (persistent): col = qrow = n0 + l31; qv[mf] = ic mf*64 + l5*32 + 0..31
  i32x8 qv[2];
  {
    const uint8_t* qp = qF + ((size_t)(b * 128 + rg) * 2) * 2048 + L * 32;
    #pragma unroll
    for (int mf = 0; mf < 2; ++mf) {
      union { uint4 u[2]; i32x8 v; } u;
      u.u[0] = *(const uint4*)(qp + mf * 2048);
      u.u[1] = *(const uint4*)(qp + mf * 2048 + 16);
      qv[mf] = u.v;
    }
  }

  f32x16 oacc[8];                                   // O^T: 256 ch x 32 qrows
  #pragma unroll
  for (int ct = 0; ct < 8; ++ct)
    #pragma unroll
    for (int i = 0; i < 16; ++i) oacc[ct][i] = 0.f;
  float lacc = 0.f;

  const uint8_t* kBase = kF + ((size_t)(b * 128) * 2) * 2048 + L * 32;
  const uint8_t* vGsrc = vF + ((size_t)(b * 64) * 8) * 2048 + L * 32;
  uint8_t* vst_w = &sm.vst[tid >> 6][0][0];

  i32x8 kv0[4], kv1[4];

  // prologue: glds vA[kb0] -> vst[0] FIRST, then K[kb0] -> kv0 (QK[0]'s K-wait
  // retires the glds too -- one-time full wait).
  {
    const int kb0 = ks * 16 + ph;
    const uint8_t* vp0 = vGsrc + (size_t)kb0 * 16384;
    #pragma unroll
    for (int ct = 0; ct < 8; ++ct)
      glds16(vp0 + ct * 2048, vst_w + ct * 1024);
    const uint8_t* kp = kBase + (size_t)kb0 * 8192;
    #pragma unroll
    for (int f = 0; f < 4; ++f) {
      union { uint4 u[2]; i32x8 v; } u;
      u.u[0] = *(const uint4*)(kp + f * 2048);
      u.u[1] = *(const uint4*)(kp + f * 2048 + 16);
      kv0[f] = u.v;
    }
  }

  for (int i2 = 0; i2 < 7; ++i2) {
    attn_body<0, true>(2 * i2,     ks, ph, L, kBase, vGsrc, vst_w, qv, kv0, kv1, oacc, lacc);
    attn_body<1, true>(2 * i2 + 1, ks, ph, L, kBase, vGsrc, vst_w, qv, kv0, kv1, oacc, lacc);
  }
  attn_body<0, true>(14, ks, ph, L, kBase, vGsrc, vst_w, qv, kv0, kv1, oacc, lacc);
  attn_body<1, false>(15, ks, ph, L, kBase, vGsrc, vst_w, qv, kv0, kv1, oacc, lacc);

  // ---- combine 4 key-quarter waves + epilogue (vst dead; overlay obuf/lsum)
  float lfin = lacc + __shfl_xor(lacc, 32, 64);

  #pragma unroll
  for (int pq = 0; pq < 4; ++pq) {
    __syncthreads();
    if (pq == 0 && lo) sm.e.lsum[ks][l31] = lfin;   // after first barrier: vst reads done
    if (ks == pq) {
      #pragma unroll
      for (int ct = 0; ct < 8; ++ct) {
        #pragma unroll
        for (int i = 0; i < 16; ++i) {
          int ch = ct * 32 + (i & 3) + 8 * (i >> 2) + 4 * l5;
          if (pq == 0) sm.e.obuf[ch][l31] = oacc[ct][i];
          else         sm.e.obuf[ch][l31] += oacc[ct][i];
        }
      }
    }
  }
  __syncthreads();

  const int row = tid & 31;
  const float coef = gamma[0] / (sm.e.lsum[0][row] + sm.e.lsum[1][row] +
                                 sm.e.lsum[2][row] + sm.e.lsum[3][row]);
  #pragma unroll 4
  for (int t = 0; t < 32; ++t) {
    int ch = (tid >> 5) + t * 8;
    size_t off = ((size_t)(b * Cn + ch)) * Nn + n0 + row;
    out[off] = sm.e.obuf[ch][row] * coef + 2.0f * x[off];
  }
}

extern "C" void kernel_launch(void* const* d_in, const int* in_sizes, int n_in,
                              void* d_out, int out_size, void* d_ws, size_t ws_size,
                              hipStream_t stream) {
  const float* x     = (const float*)d_in[0];
  const float* Wq    = (const float*)d_in[1];
  const float* bq    = (const float*)d_in[2];
  const float* Wk    = (const float*)d_in[3];
  const float* bk    = (const float*)d_in[4];
  const float* Wv    = (const float*)d_in[5];
  const float* bv    = (const float*)d_in[6];
  const float* gamma = (const float*)d_in[7];
  float* out = (float*)d_out;

  uint8_t* qF = (uint8_t*)d_ws;                       // 2 MB fp8 x64-frag-major
  uint8_t* kF = qF + (2u << 20);                      // 2 MB
  uint8_t* vF = kF + (2u << 20);                      // 4 MB
  unsigned short* wbf = (unsigned short*)(vF + (4u << 20));  // 256 KB bf16 frag-major

  hipLaunchKernelGGL(cvt_weights, dim3(64), dim3(256), 0, stream, Wq, Wk, Wv, wbf);
  hipLaunchKernelGGL(proj_kernel, dim3(128, 4), dim3(256), 0, stream,
                     x, wbf, bq, bk, bv, qF, kF, vF);
  hipLaunchKernelGGL(attn_kernel, dim3(512), dim3(256), 0, stream,
                     qF, kF, vF, x, gamma, out);
}

// Round 13
// 143.138 us; speedup vs baseline: 1.4647x; 1.4647x over previous
//
#include <hip/hip_runtime.h>
#include <stdint.h>

// BasicAttention: B=4, C=256, IC=128, N=4096, fp32 in/out.
// R20: R19's PRE-COMMITTED FALLBACK. Three spills (R13 V-rotation, R17
// setprio, R19 K-dbuf) establish the law: any 32-reg live range crossing the
// loop backedge spills at this register saturation. Only zero-VGPR prefetch
// (glds->LDS) may cross iterations. So: vA -> per-wave LDS double-buffer via
// glds16 issued 1-ahead (zero regs); K = JIT single-buffer (R12's in-iteration
// pattern, proven no-spill); vB = regs, issued early. Net -32 VGPR vs R18.
// Issue order/iter: K[t] -> vB[t] (glds vA[t] already outstanding): QK's
// K-wait retires glds+K, vB stays in flight; PV reads vA(LDS)+vB(reg);
// glds vA[t+1] last. No drains, no fences, NO setprio. R18 rotation kept
// (verified -1.7us). proj/cvt = R14 exact.
// Primary check: WRITE_SIZE==16384 && VGPR<=128. Spill => R18 is final.
// LDS: vst[4][2][8192] (64KB) unioned with epilogue; 2 blocks/CU (reg-capped
// anyway). Micros: exp2-fold, permlane32_swap, in-place exp.
// ws: qF 2MB | kF 2MB | vF 4MB | wbf(bf16) 256KB.

#define Bn 4
#define Cn 256
#define ICn 128
#define Nn 4096

typedef __attribute__((ext_vector_type(8))) short bf16x8;
typedef __attribute__((ext_vector_type(4))) float f32x4;
typedef __attribute__((ext_vector_type(16))) float f32x16;
typedef __attribute__((ext_vector_type(8))) int i32x8;

#define SCALE1 0x7f7f7f7f  // e8m0 127 (=2^0) in all 4 bytes: scale = 1.0

__device__ __forceinline__ unsigned short f2bf(float f) {
  union { float f; uint32_t u; } v; v.f = f;
  uint32_t r = (v.u + 0x7fffu + ((v.u >> 16) & 1u)) >> 16;
  return (unsigned short)r;
}

__device__ __forceinline__ uint32_t pk4_fp8(float a, float b, float c, float d) {
  int r = 0;
  r = __builtin_amdgcn_cvt_pk_fp8_f32(a, b, r, false);
  r = __builtin_amdgcn_cvt_pk_fp8_f32(c, d, r, true);
  return (uint32_t)r;
}

// async global->LDS, 16B/lane; lds dest = wave-uniform base + lane*16,
// global src is per-lane.
__device__ __forceinline__ void glds16(const uint8_t* g, uint8_t* l) {
  __builtin_amdgcn_global_load_lds((const __attribute__((address_space(1))) void*)g,
                                   (__attribute__((address_space(3))) void*)l, 16, 0, 0);
}

// wbf frag-major (bf16): [tile(32)][kk(8)][lane(64)][j(8)]; tiles 0-7 Wq, 8-15 Wk, 16-31 Wv.
__global__ __launch_bounds__(256) void cvt_weights(const float* __restrict__ Wq,
                                                   const float* __restrict__ Wk,
                                                   const float* __restrict__ Wv,
                                                   unsigned short* __restrict__ wbf) {
  int t = blockIdx.x * 256 + threadIdx.x;   // 0..16383 = tile*512 + kk*64 + lane
  int tile = t >> 9;
  int kk = (t >> 6) & 7;
  int lane = t & 63;
  const float* W; int row;
  if (tile < 8)       { W = Wq; row = tile * 16 + (lane & 15); }
  else if (tile < 16) { W = Wk; row = (tile - 8) * 16 + (lane & 15); }
  else                { W = Wv; row = (tile - 16) * 16 + (lane & 15); }
  const float* src = W + (size_t)row * Cn + kk * 32 + (lane >> 4) * 8;
  float4 f0 = *(const float4*)src;
  float4 f1 = *(const float4*)(src + 4);
  ushort4 o0, o1;
  o0.x = f2bf(f0.x); o0.y = f2bf(f0.y); o0.z = f2bf(f0.z); o0.w = f2bf(f0.w);
  o1.x = f2bf(f1.x); o1.y = f2bf(f1.y); o1.z = f2bf(f1.z); o1.w = f2bf(f1.w);
  *(ushort4*)(wbf + (size_t)t * 8)     = o0;
  *(ushort4*)(wbf + (size_t)t * 8 + 4) = o1;
}

// qF/kF fp8 x64-frag layout: [b][nt(128)][mf(2)][lane(64)][32B]; lane = l5*32+px31,
//   dword d at mf covers ic = mf*64 + l5*32 + d*4 .. +3 for pixel px.
// vF fp8 x64-frag layout: [b][kb64(64)][ct(8)][lane(64)][32B]; lane = l5*32+ch31,
//   dword d covers keys = l5*32 + d*4 .. +3 (within the 64-key block) for ch.
// wave0: q, wave1: k, waves 2-3: v (8 vtg each).
__global__ __launch_bounds__(256, 2) void proj_kernel(const float* __restrict__ x,
                                                      const unsigned short* __restrict__ wbf,
                                                      const float* __restrict__ bq,
                                                      const float* __restrict__ bk,
                                                      const float* __restrict__ bv,
                                                      uint8_t* __restrict__ qF,
                                                      uint8_t* __restrict__ kF,
                                                      uint8_t* __restrict__ vF) {
  const int b = blockIdx.y;
  const int ntile = blockIdx.x;            // 32-pixel tile
  const int px0 = ntile * 32;
  const int tid = threadIdx.x;
  const int lane = tid & 63;
  const int w = tid >> 6;
  const int c0 = lane & 15, g = lane >> 4;
  // 128^-0.25 * sqrt(log2(e)), folded into BOTH q and k: S comes out in log2
  // domain so attn softmax is a bare v_exp_f32 (2^x).
  const float hscale = 0.3570958292f;

  __shared__ __align__(16) unsigned short xT[32][264];  // [px][c] (16.9 KB)
  __shared__ __align__(16) uint8_t tb[4][4096];         // per-wave store-staging (16 KB)

  #pragma unroll
  for (int t = 0; t < 8; ++t) {            // 8 c-rows x 128B contiguous per wave-instr
    int c = (tid >> 3) + t * 32;
    int i8 = tid & 7;
    float4 f4 = *(const float4*)(x + ((size_t)(b * Cn + c)) * Nn + px0 + i8 * 4);
    xT[i8 * 4 + 0][c] = f2bf(f4.x);
    xT[i8 * 4 + 1][c] = f2bf(f4.y);
    xT[i8 * 4 + 2][c] = f2bf(f4.z);
    xT[i8 * 4 + 3][c] = f2bf(f4.w);
  }
  __syncthreads();

  bf16x8 a[2][8];   // x frags for both 16-px halves
  #pragma unroll
  for (int h = 0; h < 2; ++h)
    #pragma unroll
    for (int kk = 0; kk < 8; ++kk)
      a[h][kk] = *(const bf16x8*)&xT[h * 16 + c0][kk * 32 + g * 8];

  f32x4 zero = {0.f, 0.f, 0.f, 0.f};
  uint8_t* tw = &tb[w][0];

  if (w < 2) {
    // wave0: q (wbf tiles 0-7), wave1: k (tiles 8-15). A = W (m=ic), B = x^T (n=px).
    const int isq = (w == 0);
    const float* bias = isq ? bq : bk;
    uint8_t* dst = isq ? qF : kF;
    #pragma unroll
    for (int otl = 0; otl < 8; ++otl) {
      const int wt = (isq ? 0 : 8) + otl;
      bf16x8 wf[8];
      #pragma unroll
      for (int kk = 0; kk < 8; ++kk)
        wf[kk] = *(const bf16x8*)(wbf + (((size_t)wt * 8 + kk) << 9) + lane * 8);
      float4 bz = *(const float4*)(bias + otl * 16 + g * 4);
      #pragma unroll
      for (int h = 0; h < 2; ++h) {
        f32x4 acc = zero;
        #pragma unroll
        for (int kk = 0; kk < 8; ++kk)
          acc = __builtin_amdgcn_mfma_f32_16x16x32_bf16(wf[kk], a[h][kk], acc, 0, 0, 0);
        // D: row = ic = otl*16 + g*4 + r, col = px = h*16 + c0
        uint32_t d = pk4_fp8((acc[0] + bz.x) * hscale, (acc[1] + bz.y) * hscale,
                             (acc[2] + bz.z) * hscale, (acc[3] + bz.w) * hscale);
        // dword D = ic/4 = otl*4+g in [0,32): mf = D>>4, l5 = (D>>3)&1, d = D&7
        int D = otl * 4 + g;
        int off = ((D >> 4) << 11) + (((((D >> 3) & 1) << 5) + h * 16 + c0) << 5) + ((D & 7) << 2);
        *(uint32_t*)(tw + off) = d;            // ds_write_b32 (cheap scatter)
      }
    }
    // coalesced store-back: flat LDS layout == flat global frag layout
    size_t base = ((size_t)(b * 128 + ntile)) << 12;   // 4096B per (b,ntile)
    #pragma unroll
    for (int r = 0; r < 4; ++r) {
      uint4 v = *(const uint4*)(tw + r * 1024 + lane * 16);
      *(uint4*)(dst + base + r * 1024 + lane * 16) = v;
    }
  } else {
    // waves 2,3: v tiles. A = x (m=px), B = W^T (n=ch).
    #pragma unroll
    for (int oi = 0; oi < 8; ++oi) {
      const int vtg = (w - 2) * 8 + oi;
      bf16x8 wf[8];
      #pragma unroll
      for (int kk = 0; kk < 8; ++kk)
        wf[kk] = *(const bf16x8*)(wbf + (((size_t)(16 + vtg) * 8 + kk) << 9) + lane * 8);
      const float bias = bv[vtg * 16 + c0];
      #pragma unroll
      for (int h = 0; h < 2; ++h) {
        f32x4 acc = zero;
        #pragma unroll
        for (int kk = 0; kk < 8; ++kk)
          acc = __builtin_amdgcn_mfma_f32_16x16x32_bf16(a[h][kk], wf[kk], acc, 0, 0, 0);
        // D: row = key = px0 + h*16 + g*4 + r, col = ch = vtg*16 + c0
        uint32_t d = pk4_fp8(acc[0] + bias, acc[1] + bias, acc[2] + bias, acc[3] + bias);
        // tb: [ct_local(4)][ch31(32)][32B], dword = h*4+g
        int off = (((vtg >> 1) & 3) << 10) + ((((vtg & 1) << 4) + c0) << 5) + ((h * 4 + g) << 2);
        *(uint32_t*)(tw + off) = d;            // ds_write_b32
      }
    }
    // coalesced store-back: 2 rounds x (two 1KB segments per wave-instr)
    const int ctb = (w - 2) * 4;
    size_t base0 = (((size_t)(b * 64 + (ntile >> 1)) * 8 + ctb) << 11)
                 + (size_t)(((ntile & 1) << 5) << 5);      // lane-half select
    #pragma unroll
    for (int r = 0; r < 2; ++r) {
      int ctl = r * 2 + (lane >> 5);
      int li = lane & 31;
      const uint8_t* s = tw + r * 2048 + lane * 32;
      uint4 v0 = *(const uint4*)(s);
      uint4 v1 = *(const uint4*)(s + 16);
      uint8_t* gp = vF + base0 + ((size_t)ctl << 11) + li * 32;
      *(uint4*)(gp) = v0;
      *(uint4*)(gp + 16) = v1;
    }
  }
}

// attn: 512 blocks x 256 thr (4 waves = 4 key-quarters), 32 q-rows/block,
// 16 iters x 64 keys, all-MX x64 MFMAs. K JIT + vA glds-LDS-dbuf + rotation.
__global__ __launch_bounds__(256, 2) void attn_kernel(const uint8_t* __restrict__ qF,
                                                      const uint8_t* __restrict__ kF,
                                                      const uint8_t* __restrict__ vF,
                                                      const float* __restrict__ x,
                                                      const float* __restrict__ gamma,
                                                      float* __restrict__ out) {
  const int blk = blockIdx.x;
  const int b = (blk & 7) >> 1;                     // 2 XCDs/batch: q+k+v 2MB < 4MB L2
  const int rg = (blk >> 3) | ((blk & 1) << 6);     // 0..127
  const int n0 = rg * 32;
  const int ph = (blk >> 3) & 15;                   // key-loop phase (R18: -1.7us)
  const int tid = threadIdx.x;
  const int L = tid & 63;
  const int ks = tid >> 6;                          // key quarter
  const int l31 = L & 31, l5 = L >> 5;
  const bool lo = (l5 == 0);

  __shared__ __align__(16) union SM {
    uint8_t vst[4][2][8192];                        // per-wave vA double-buffer (64 KB)
    struct { float obuf[256][33]; float lsum[4][32]; } e;   // epilogue overlay
  } sm;

  // Q B-frags (persistent): col = qrow = n0 + l31; qv[mf] = ic mf*64 + l5*32 + 0..31
  i32x8 qv[2];
  {
    const uint8_t* qp = qF + ((size_t)(b * 128 + rg) * 2) * 2048 + L * 32;
    #pragma unroll
    for (int mf = 0; mf < 2; ++mf) {
      union { uint4 u[2]; i32x8 v; } u;
      u.u[0] = *(const uint4*)(qp + mf * 2048);
      u.u[1] = *(const uint4*)(qp + mf * 2048 + 16);
      qv[mf] = u.v;
    }
  }

  f32x16 oacc[8];                                   // O^T: 256 ch x 32 qrows
  #pragma unroll
  for (int ct = 0; ct < 8; ++ct)
    #pragma unroll
    for (int i = 0; i < 16; ++i) oacc[ct][i] = 0.f;
  float lacc = 0.f;

  const uint8_t* kBase = kF + ((size_t)(b * 128) * 2) * 2048 + L * 32;
  const uint8_t* vBase = vF + ((size_t)(b * 64) * 8) * 2048 + L * 32;
  uint8_t* vst_w = &sm.vst[tid >> 6][0][0];

  // prologue: glds vA[kb0] -> vst[0] only (zero VGPR; K is loaded in-loop JIT)
  {
    const int kb0 = ks * 16 + ph;
    const uint8_t* vp0 = vBase + (size_t)kb0 * 16384;
    #pragma unroll
    for (int ct = 0; ct < 8; ++ct)
      glds16(vp0 + ct * 2048, vst_w + ct * 1024);
  }

  for (int it = 0; it < 16; ++it) {
    const int cur = it & 1;
    const int kb = ks * 16 + ((it + ph) & 15);      // rotated 64-key block
    const uint8_t* vp = vBase + (size_t)kb * 16384;

    // (1) K frags JIT, issued FIRST. QK's K-wait retires the older glds vA[t]
    //     (needed this iter anyway) + K; the younger vB stays in flight.
    i32x8 kv[4];                                    // [tile*2 + mf]
    {
      const uint8_t* kp = kBase + (size_t)kb * 8192;
      #pragma unroll
      for (int f = 0; f < 4; ++f) {
        union { uint4 u[2]; i32x8 v; } u;
        u.u[0] = *(const uint4*)(kp + f * 2048);
        u.u[1] = *(const uint4*)(kp + f * 2048 + 16);
        kv[f] = u.v;
      }
    }

    // (2) vB[t] register loads (keys l5*32+16..31 halves); consumed at PV.
    uint4 vB[8];
    #pragma unroll
    for (int ct = 0; ct < 8; ++ct) vB[ct] = *(const uint4*)(vp + ct * 2048 + 16);

    // (3) QK tile1 (keys 0-31), K=128 via 2 x64 steps. S^T: col=l31=qrow,
    //     row(reg i) = key = (i&3)+8*(i>>2)+4*l5.
    f32x16 s;
    #pragma unroll
    for (int i = 0; i < 16; ++i) s[i] = 0.f;
    s = __builtin_amdgcn_mfma_scale_f32_32x32x64_f8f6f4(kv[0], qv[0], s, 0, 0, 0, SCALE1, 0, SCALE1);
    s = __builtin_amdgcn_mfma_scale_f32_32x32x64_f8f6f4(kv[1], qv[1], s, 0, 0, 0, SCALE1, 0, SCALE1);
    // exp/pack tile1 (one S tile live at a time; VGPR cap)
    #pragma unroll
    for (int i = 0; i < 16; ++i) {
      float r;
      asm("v_exp_f32 %0, %1" : "=v"(r) : "v"(s[i]));
      s[i] = r;
    }
    #pragma unroll
    for (int i = 0; i < 16; ++i) lacc += s[i];
    uint32_t d0 = pk4_fp8(s[0], s[1], s[2], s[3]);      // keys lo:0-3  hi:4-7
    uint32_t d1 = pk4_fp8(s[4], s[5], s[6], s[7]);      // keys lo:8-11 hi:12-15
    uint32_t d2 = pk4_fp8(s[8], s[9], s[10], s[11]);    // keys lo:16-19 hi:20-23
    uint32_t d3 = pk4_fp8(s[12], s[13], s[14], s[15]);  // keys lo:24-27 hi:28-31

    // (4) QK tile2 (keys 32-63)
    #pragma unroll
    for (int i = 0; i < 16; ++i) s[i] = 0.f;
    s = __builtin_amdgcn_mfma_scale_f32_32x32x64_f8f6f4(kv[2], qv[0], s, 0, 0, 0, SCALE1, 0, SCALE1);
    s = __builtin_amdgcn_mfma_scale_f32_32x32x64_f8f6f4(kv[3], qv[1], s, 0, 0, 0, SCALE1, 0, SCALE1);

    #pragma unroll
    for (int i = 0; i < 16; ++i) {
      float r;
      asm("v_exp_f32 %0, %1" : "=v"(r) : "v"(s[i]));
      s[i] = r;
    }
    #pragma unroll
    for (int i = 0; i < 16; ++i) lacc += s[i];
    uint32_t e0 = pk4_fp8(s[0], s[1], s[2], s[3]);
    uint32_t e1 = pk4_fp8(s[4], s[5], s[6], s[7]);
    uint32_t e2 = pk4_fp8(s[8], s[9], s[10], s[11]);
    uint32_t e3 = pk4_fp8(s[12], s[13], s[14], s[15]);

    // (5) P^T B-frag (K=64): swap(a=e_i, b=d_i); w[2i]=b_i, w[2i+1]=a_i
    //     (lo lanes keys 0-31 = tile1, hi lanes keys 32-63 = tile2). No selects.
    union { uint32_t w[8]; i32x8 v; } pf;
    {
      uint32_t a0 = e0, b0 = d0;
      asm("v_permlane32_swap_b32 %0, %1" : "+v"(a0), "+v"(b0));
      pf.w[0] = b0; pf.w[1] = a0;
      uint32_t a1 = e1, b1 = d1;
      asm("v_permlane32_swap_b32 %0, %1" : "+v"(a1), "+v"(b1));
      pf.w[2] = b1; pf.w[3] = a1;
      uint32_t a2 = e2, b2 = d2;
      asm("v_permlane32_swap_b32 %0, %1" : "+v"(a2), "+v"(b2));
      pf.w[4] = b2; pf.w[5] = a2;
      uint32_t a3 = e3, b3 = d3;
      asm("v_permlane32_swap_b32 %0, %1" : "+v"(a3), "+v"(b3));
      pf.w[6] = b3; pf.w[7] = a3;
    }

    // (6) PV: vA from LDS (glds'ed last iter; retired by this iter's K-wait)
    //     + vB regs. D layout unchanged -> epilogue unchanged.
    #pragma unroll
    for (int ct = 0; ct < 8; ++ct) {
      union { uint4 u[2]; i32x8 v; } va;
      va.u[0] = *(const uint4*)(vst_w + cur * 8192 + ct * 1024 + (size_t)L * 16);
      va.u[1] = vB[ct];
      oacc[ct] = __builtin_amdgcn_mfma_scale_f32_32x32x64_f8f6f4(va.v, pf.v, oacc[ct], 0, 0, 0, SCALE1, 0, SCALE1);
    }

    // (7) glds vA[t+1] -> vst[cur^1] (async, zero VGPR; full QK+exp to land)
    if (it < 15) {
      const int kbn = ks * 16 + ((it + 1 + ph) & 15);
      const uint8_t* vpn = vBase + (size_t)kbn * 16384;
      uint8_t* ldst = vst_w + (cur ^ 1) * 8192;
      #pragma unroll
      for (int ct = 0; ct < 8; ++ct)
        glds16(vpn + ct * 2048, ldst + ct * 1024);
    }
  }

  // ---- combine 4 key-quarter waves + epilogue (vst dead; overlay obuf/lsum)
  float lfin = lacc + __shfl_xor(lacc, 32, 64);

  #pragma unroll
  for (int pq = 0; pq < 4; ++pq) {
    __syncthreads();
    if (pq == 0 && lo) sm.e.lsum[ks][l31] = lfin;   // after first barrier: vst reads done
    if (ks == pq) {
      #pragma unroll
      for (int ct = 0; ct < 8; ++ct) {
        #pragma unroll
        for (int i = 0; i < 16; ++i) {
          int ch = ct * 32 + (i & 3) + 8 * (i >> 2) + 4 * l5;
          if (pq == 0) sm.e.obuf[ch][l31] = oacc[ct][i];
          else         sm.e.obuf[ch][l31] += oacc[ct][i];
        }
      }
    }
  }
  __syncthreads();

  const int row = tid & 31;
  const float coef = gamma[0] / (sm.e.lsum[0][row] + sm.e.lsum[1][row] +
                                 sm.e.lsum[2][row] + sm.e.lsum[3][row]);
  #pragma unroll 4
  for (int t = 0; t < 32; ++t) {
    int ch = (tid >> 5) + t * 8;
    size_t off = ((size_t)(b * Cn + ch)) * Nn + n0 + row;
    out[off] = sm.e.obuf[ch][row] * coef + 2.0f * x[off];
  }
}

extern "C" void kernel_launch(void* const* d_in, const int* in_sizes, int n_in,
                              void* d_out, int out_size, void* d_ws, size_t ws_size,
                              hipStream_t stream) {
  const float* x     = (const float*)d_in[0];
  const float* Wq    = (const float*)d_in[1];
  const float* bq    = (const float*)d_in[2];
  const float* Wk    = (const float*)d_in[3];
  const float* bk    = (const float*)d_in[4];
  const float* Wv    = (const float*)d_in[5];
  const float* bv    = (const float*)d_in[6];
  const float* gamma = (const float*)d_in[7];
  float* out = (float*)d_out;

  uint8_t* qF = (uint8_t*)d_ws;                       // 2 MB fp8 x64-frag-major
  uint8_t* kF = qF + (2u << 20);                      // 2 MB
  uint8_t* vF = kF + (2u << 20);                      // 4 MB
  unsigned short* wbf = (unsigned short*)(vF + (4u << 20));  // 256 KB bf16 frag-major

  hipLaunchKernelGGL(cvt_weights, dim3(64), dim3(256), 0, stream, Wq, Wk, Wv, wbf);
  hipLaunchKernelGGL(proj_kernel, dim3(128, 4), dim3(256), 0, stream,
                     x, wbf, bq, bk, bv, qF, kF, vF);
  hipLaunchKernelGGL(attn_kernel, dim3(512), dim3(256), 0, stream,
                     qF, kF, vF, x, gamma, out);
}

// Round 14
// 129.514 us; speedup vs baseline: 1.6188x; 1.1052x over previous
//
#include <hip/hip_runtime.h>
#include <stdint.h>

// BasicAttention: B=4, C=256, IC=128, N=4096, fp32 in/out.
// R21: R18 (best verified: attn 46.8us, total 129.3us) + linear two-segment
// rotation loop. R20 closed the glds question: LDS-consumed prefetch always
// loses here (compiler guards ds_read with conservative vmcnt -> drains the
// younger reg loads; 61.5us). Session law: only R18's shape works -- direct
// per-register loads, JIT-K issued first, vB early, depth-0/1, no fences, no
// setprio, no cross-backedge reg live ranges. This round's only change:
// rotation via two linear kb segments (kb0..end, start..kb0) instead of the
// per-iter (it+ph)&15 mask, so kb is a plain induction var and the compiler
// strength-reduces the 20 load addrs/iter to pointer increments (VALU is ~2x
// softmax-core; address math is part of the bloat). Zero new registers.
// Check: WRITE==16384, VGPR<=128. Neutral => structural limit (128-AGPR acc
// caps occupancy at 2 waves/SIMD; alternative tilings raise L2 traffic past
// the latency gain) and this stands final.
// proj/cvt = R14 exact. Micros: exp2-fold, permlane32_swap, in-place exp.
// ws: qF 2MB | kF 2MB | vF 4MB | wbf(bf16) 256KB.

#define Bn 4
#define Cn 256
#define ICn 128
#define Nn 4096

typedef __attribute__((ext_vector_type(8))) short bf16x8;
typedef __attribute__((ext_vector_type(4))) float f32x4;
typedef __attribute__((ext_vector_type(16))) float f32x16;
typedef __attribute__((ext_vector_type(8))) int i32x8;

#define SCALE1 0x7f7f7f7f  // e8m0 127 (=2^0) in all 4 bytes: scale = 1.0

__device__ __forceinline__ unsigned short f2bf(float f) {
  union { float f; uint32_t u; } v; v.f = f;
  uint32_t r = (v.u + 0x7fffu + ((v.u >> 16) & 1u)) >> 16;
  return (unsigned short)r;
}

__device__ __forceinline__ uint32_t pk4_fp8(float a, float b, float c, float d) {
  int r = 0;
  r = __builtin_amdgcn_cvt_pk_fp8_f32(a, b, r, false);
  r = __builtin_amdgcn_cvt_pk_fp8_f32(c, d, r, true);
  return (uint32_t)r;
}

// wbf frag-major (bf16): [tile(32)][kk(8)][lane(64)][j(8)]; tiles 0-7 Wq, 8-15 Wk, 16-31 Wv.
__global__ __launch_bounds__(256) void cvt_weights(const float* __restrict__ Wq,
                                                   const float* __restrict__ Wk,
                                                   const float* __restrict__ Wv,
                                                   unsigned short* __restrict__ wbf) {
  int t = blockIdx.x * 256 + threadIdx.x;   // 0..16383 = tile*512 + kk*64 + lane
  int tile = t >> 9;
  int kk = (t >> 6) & 7;
  int lane = t & 63;
  const float* W; int row;
  if (tile < 8)       { W = Wq; row = tile * 16 + (lane & 15); }
  else if (tile < 16) { W = Wk; row = (tile - 8) * 16 + (lane & 15); }
  else                { W = Wv; row = (tile - 16) * 16 + (lane & 15); }
  const float* src = W + (size_t)row * Cn + kk * 32 + (lane >> 4) * 8;
  float4 f0 = *(const float4*)src;
  float4 f1 = *(const float4*)(src + 4);
  ushort4 o0, o1;
  o0.x = f2bf(f0.x); o0.y = f2bf(f0.y); o0.z = f2bf(f0.z); o0.w = f2bf(f0.w);
  o1.x = f2bf(f1.x); o1.y = f2bf(f1.y); o1.z = f2bf(f1.z); o1.w = f2bf(f1.w);
  *(ushort4*)(wbf + (size_t)t * 8)     = o0;
  *(ushort4*)(wbf + (size_t)t * 8 + 4) = o1;
}

// qF/kF fp8 x64-frag layout: [b][nt(128)][mf(2)][lane(64)][32B]; lane = l5*32+px31,
//   dword d at mf covers ic = mf*64 + l5*32 + d*4 .. +3 for pixel px.
// vF fp8 x64-frag layout: [b][kb64(64)][ct(8)][lane(64)][32B]; lane = l5*32+ch31,
//   dword d covers keys = l5*32 + d*4 .. +3 (within the 64-key block) for ch.
// wave0: q, wave1: k, waves 2-3: v (8 vtg each).
__global__ __launch_bounds__(256, 2) void proj_kernel(const float* __restrict__ x,
                                                      const unsigned short* __restrict__ wbf,
                                                      const float* __restrict__ bq,
                                                      const float* __restrict__ bk,
                                                      const float* __restrict__ bv,
                                                      uint8_t* __restrict__ qF,
                                                      uint8_t* __restrict__ kF,
                                                      uint8_t* __restrict__ vF) {
  const int b = blockIdx.y;
  const int ntile = blockIdx.x;            // 32-pixel tile
  const int px0 = ntile * 32;
  const int tid = threadIdx.x;
  const int lane = tid & 63;
  const int w = tid >> 6;
  const int c0 = lane & 15, g = lane >> 4;
  // 128^-0.25 * sqrt(log2(e)), folded into BOTH q and k: S comes out in log2
  // domain so attn softmax is a bare v_exp_f32 (2^x).
  const float hscale = 0.3570958292f;

  __shared__ __align__(16) unsigned short xT[32][264];  // [px][c] (16.9 KB)
  __shared__ __align__(16) uint8_t tb[4][4096];         // per-wave store-staging (16 KB)

  #pragma unroll
  for (int t = 0; t < 8; ++t) {            // 8 c-rows x 128B contiguous per wave-instr
    int c = (tid >> 3) + t * 32;
    int i8 = tid & 7;
    float4 f4 = *(const float4*)(x + ((size_t)(b * Cn + c)) * Nn + px0 + i8 * 4);
    xT[i8 * 4 + 0][c] = f2bf(f4.x);
    xT[i8 * 4 + 1][c] = f2bf(f4.y);
    xT[i8 * 4 + 2][c] = f2bf(f4.z);
    xT[i8 * 4 + 3][c] = f2bf(f4.w);
  }
  __syncthreads();

  bf16x8 a[2][8];   // x frags for both 16-px halves
  #pragma unroll
  for (int h = 0; h < 2; ++h)
    #pragma unroll
    for (int kk = 0; kk < 8; ++kk)
      a[h][kk] = *(const bf16x8*)&xT[h * 16 + c0][kk * 32 + g * 8];

  f32x4 zero = {0.f, 0.f, 0.f, 0.f};
  uint8_t* tw = &tb[w][0];

  if (w < 2) {
    // wave0: q (wbf tiles 0-7), wave1: k (tiles 8-15). A = W (m=ic), B = x^T (n=px).
    const int isq = (w == 0);
    const float* bias = isq ? bq : bk;
    uint8_t* dst = isq ? qF : kF;
    #pragma unroll
    for (int otl = 0; otl < 8; ++otl) {
      const int wt = (isq ? 0 : 8) + otl;
      bf16x8 wf[8];
      #pragma unroll
      for (int kk = 0; kk < 8; ++kk)
        wf[kk] = *(const bf16x8*)(wbf + (((size_t)wt * 8 + kk) << 9) + lane * 8);
      float4 bz = *(const float4*)(bias + otl * 16 + g * 4);
      #pragma unroll
      for (int h = 0; h < 2; ++h) {
        f32x4 acc = zero;
        #pragma unroll
        for (int kk = 0; kk < 8; ++kk)
          acc = __builtin_amdgcn_mfma_f32_16x16x32_bf16(wf[kk], a[h][kk], acc, 0, 0, 0);
        // D: row = ic = otl*16 + g*4 + r, col = px = h*16 + c0
        uint32_t d = pk4_fp8((acc[0] + bz.x) * hscale, (acc[1] + bz.y) * hscale,
                             (acc[2] + bz.z) * hscale, (acc[3] + bz.w) * hscale);
        // dword D = ic/4 = otl*4+g in [0,32): mf = D>>4, l5 = (D>>3)&1, d = D&7
        int D = otl * 4 + g;
        int off = ((D >> 4) << 11) + (((((D >> 3) & 1) << 5) + h * 16 + c0) << 5) + ((D & 7) << 2);
        *(uint32_t*)(tw + off) = d;            // ds_write_b32 (cheap scatter)
      }
    }
    // coalesced store-back: flat LDS layout == flat global frag layout
    size_t base = ((size_t)(b * 128 + ntile)) << 12;   // 4096B per (b,ntile)
    #pragma unroll
    for (int r = 0; r < 4; ++r) {
      uint4 v = *(const uint4*)(tw + r * 1024 + lane * 16);
      *(uint4*)(dst + base + r * 1024 + lane * 16) = v;
    }
  } else {
    // waves 2,3: v tiles. A = x (m=px), B = W^T (n=ch).
    #pragma unroll
    for (int oi = 0; oi < 8; ++oi) {
      const int vtg = (w - 2) * 8 + oi;
      bf16x8 wf[8];
      #pragma unroll
      for (int kk = 0; kk < 8; ++kk)
        wf[kk] = *(const bf16x8*)(wbf + (((size_t)(16 + vtg) * 8 + kk) << 9) + lane * 8);
      const float bias = bv[vtg * 16 + c0];
      #pragma unroll
      for (int h = 0; h < 2; ++h) {
        f32x4 acc = zero;
        #pragma unroll
        for (int kk = 0; kk < 8; ++kk)
          acc = __builtin_amdgcn_mfma_f32_16x16x32_bf16(a[h][kk], wf[kk], acc, 0, 0, 0);
        // D: row = key = px0 + h*16 + g*4 + r, col = ch = vtg*16 + c0
        uint32_t d = pk4_fp8(acc[0] + bias, acc[1] + bias, acc[2] + bias, acc[3] + bias);
        // tb: [ct_local(4)][ch31(32)][32B], dword = h*4+g
        int off = (((vtg >> 1) & 3) << 10) + ((((vtg & 1) << 4) + c0) << 5) + ((h * 4 + g) << 2);
        *(uint32_t*)(tw + off) = d;            // ds_write_b32
      }
    }
    // coalesced store-back: 2 rounds x (two 1KB segments per wave-instr)
    const int ctb = (w - 2) * 4;
    size_t base0 = (((size_t)(b * 64 + (ntile >> 1)) * 8 + ctb) << 11)
                 + (size_t)(((ntile & 1) << 5) << 5);      // lane-half select
    #pragma unroll
    for (int r = 0; r < 2; ++r) {
      int ctl = r * 2 + (lane >> 5);
      int li = lane & 31;
      const uint8_t* s = tw + r * 2048 + lane * 32;
      uint4 v0 = *(const uint4*)(s);
      uint4 v1 = *(const uint4*)(s + 16);
      uint8_t* gp = vF + base0 + ((size_t)ctl << 11) + li * 32;
      *(uint4*)(gp) = v0;
      *(uint4*)(gp + 16) = v1;
    }
  }
}

// One 64-key iteration, EXACT R18 body shape (K JIT first, vA/vB reg loads,
// no fences). kb is a linear induction variable in the caller's segments.
__device__ __forceinline__ void attn_iter(int kb, int L,
                                          const uint8_t* kBase, const uint8_t* vBase,
                                          const i32x8 (&qv)[2],
                                          f32x16 (&oacc)[8], float& lacc) {
  const uint8_t* vp = vBase + (size_t)kb * 16384;

  // (1) K frags JIT, issued FIRST: QK's vmcnt wait retires these while the
  //     later-issued V loads stay in flight (in-order retirement).
  i32x8 kv[4];                                    // [tile*2 + mf]
  {
    const uint8_t* kp = kBase + (size_t)kb * 8192;
    #pragma unroll
    for (int f = 0; f < 4; ++f) {
      union { uint4 u[2]; i32x8 v; } u;
      u.u[0] = *(const uint4*)(kp + f * 2048);
      u.u[1] = *(const uint4*)(kp + f * 2048 + 16);
      kv[f] = u.v;
    }
  }

  // (2) V dword-half A; half B issued mid-iter to cap live VGPRs.
  uint4 vA[8], vB[8];
  #pragma unroll
  for (int ct = 0; ct < 8; ++ct) vA[ct] = *(const uint4*)(vp + ct * 2048);

  // (3) QK tile1 (keys 0-31), K=128 via 2 x64 steps. S^T: col=l31=qrow,
  //     row(reg i) = key = (i&3)+8*(i>>2)+4*l5.
  f32x16 s;
  #pragma unroll
  for (int i = 0; i < 16; ++i) s[i] = 0.f;
  s = __builtin_amdgcn_mfma_scale_f32_32x32x64_f8f6f4(kv[0], qv[0], s, 0, 0, 0, SCALE1, 0, SCALE1);
  s = __builtin_amdgcn_mfma_scale_f32_32x32x64_f8f6f4(kv[1], qv[1], s, 0, 0, 0, SCALE1, 0, SCALE1);
  // exp/pack tile1 (one S tile live at a time; VGPR cap)
  #pragma unroll
  for (int i = 0; i < 16; ++i) {
    float r;
    asm("v_exp_f32 %0, %1" : "=v"(r) : "v"(s[i]));
    s[i] = r;
  }
  #pragma unroll
  for (int i = 0; i < 16; ++i) lacc += s[i];
  uint32_t d0 = pk4_fp8(s[0], s[1], s[2], s[3]);      // keys lo:0-3  hi:4-7
  uint32_t d1 = pk4_fp8(s[4], s[5], s[6], s[7]);      // keys lo:8-11 hi:12-15
  uint32_t d2 = pk4_fp8(s[8], s[9], s[10], s[11]);    // keys lo:16-19 hi:20-23
  uint32_t d3 = pk4_fp8(s[12], s[13], s[14], s[15]);  // keys lo:24-27 hi:28-31

  // (4) QK tile2 (keys 32-63)
  #pragma unroll
  for (int i = 0; i < 16; ++i) s[i] = 0.f;
  s = __builtin_amdgcn_mfma_scale_f32_32x32x64_f8f6f4(kv[2], qv[0], s, 0, 0, 0, SCALE1, 0, SCALE1);
  s = __builtin_amdgcn_mfma_scale_f32_32x32x64_f8f6f4(kv[3], qv[1], s, 0, 0, 0, SCALE1, 0, SCALE1);

  // (5) V dword-half B issue (covered by exp-t2 + swaps + PV front)
  #pragma unroll
  for (int ct = 0; ct < 8; ++ct) vB[ct] = *(const uint4*)(vp + ct * 2048 + 16);

  #pragma unroll
  for (int i = 0; i < 16; ++i) {
    float r;
    asm("v_exp_f32 %0, %1" : "=v"(r) : "v"(s[i]));
    s[i] = r;
  }
  #pragma unroll
  for (int i = 0; i < 16; ++i) lacc += s[i];
  uint32_t e0 = pk4_fp8(s[0], s[1], s[2], s[3]);
  uint32_t e1 = pk4_fp8(s[4], s[5], s[6], s[7]);
  uint32_t e2 = pk4_fp8(s[8], s[9], s[10], s[11]);
  uint32_t e3 = pk4_fp8(s[12], s[13], s[14], s[15]);

  // (6) P^T B-frag (K=64): swap(a=e_i, b=d_i); w[2i]=b_i, w[2i+1]=a_i
  //     (lo lanes keys 0-31 = tile1, hi lanes keys 32-63 = tile2). No selects.
  union { uint32_t w[8]; i32x8 v; } pf;
  {
    uint32_t a0 = e0, b0 = d0;
    asm("v_permlane32_swap_b32 %0, %1" : "+v"(a0), "+v"(b0));
    pf.w[0] = b0; pf.w[1] = a0;
    uint32_t a1 = e1, b1 = d1;
    asm("v_permlane32_swap_b32 %0, %1" : "+v"(a1), "+v"(b1));
    pf.w[2] = b1; pf.w[3] = a1;
    uint32_t a2 = e2, b2 = d2;
    asm("v_permlane32_swap_b32 %0, %1" : "+v"(a2), "+v"(b2));
    pf.w[4] = b2; pf.w[5] = a2;
    uint32_t a3 = e3, b3 = d3;
    asm("v_permlane32_swap_b32 %0, %1" : "+v"(a3), "+v"(b3));
    pf.w[6] = b3; pf.w[7] = a3;
  }

  // (7) O^T += V·P^T: 8 x64 MFMAs. D layout fixed -> epilogue unchanged.
  #pragma unroll
  for (int ct = 0; ct < 8; ++ct) {
    union { uint4 u[2]; i32x8 v; } va;
    va.u[0] = vA[ct]; va.u[1] = vB[ct];
    oacc[ct] = __builtin_amdgcn_mfma_scale_f32_32x32x64_f8f6f4(va.v, pf.v, oacc[ct], 0, 0, 0, SCALE1, 0, SCALE1);
  }
}

// attn: 512 blocks x 256 thr (4 waves = 4 key-quarters), 32 q-rows/block,
// 16 iters x 64 keys, all-MX x64 MFMAs. R18 body, two linear kb segments.
__global__ __launch_bounds__(256, 2) void attn_kernel(const uint8_t* __restrict__ qF,
                                                      const uint8_t* __restrict__ kF,
                                                      const uint8_t* __restrict__ vF,
                                                      const float* __restrict__ x,
                                                      const float* __restrict__ gamma,
                                                      float* __restrict__ out) {
  const int blk = blockIdx.x;
  const int b = (blk & 7) >> 1;                     // 2 XCDs/batch: q+k+v 2MB < 4MB L2
  const int rg = (blk >> 3) | ((blk & 1) << 6);     // 0..127
  const int n0 = rg * 32;
  const int ph = (blk >> 3) & 15;                   // key-loop phase (R18: -1.7us)
  const int tid = threadIdx.x;
  const int L = tid & 63;
  const int ks = tid >> 6;                          // key quarter
  const int l31 = L & 31, l5 = L >> 5;
  const bool lo = (l5 == 0);

  __shared__ __align__(16) struct SM {
    float obuf[256][33];                            // epilogue O^T combine (33.8 KB)
    float lsum[4][32];
  } sm;

  // Q B-frags (persistent): col = qrow = n0 + l31; qv[mf] = ic mf*64 + l5*32 + 0..31
  i32x8 qv[2];
  {
    const uint8_t* qp = qF + ((size_t)(b * 128 + rg) * 2) * 2048 + L * 32;
    #pragma unroll
    for (int mf = 0; mf < 2; ++mf) {
      union { uint4 u[2]; i32x8 v; } u;
      u.u[0] = *(const uint4*)(qp + mf * 2048);
      u.u[1] = *(const uint4*)(qp + mf * 2048 + 16);
      qv[mf] = u.v;
    }
  }

  f32x16 oacc[8];                                   // O^T: 256 ch x 32 qrows
  #pragma unroll
  for (int ct = 0; ct < 8; ++ct)
    #pragma unroll
    for (int i = 0; i < 16; ++i) oacc[ct][i] = 0.f;
  float lacc = 0.f;

  const uint8_t* kBase = kF + ((size_t)(b * 128) * 2) * 2048 + L * 32;
  const uint8_t* vBase = vF + ((size_t)(b * 64) * 8) * 2048 + L * 32;

  // rotated key loop as two LINEAR segments: kb = kb0..end, then start..kb0.
  // (sum over keys commutes; linear kb -> compiler strength-reduces kp/vp to
  // pointer increments instead of per-iter mask+mul address rebuilds)
  const int kbS = ks * 16;
  const int kb0 = kbS + ph;
  for (int kb = kb0; kb < kbS + 16; ++kb)
    attn_iter(kb, L, kBase, vBase, qv, oacc, lacc);
  for (int kb = kbS; kb < kb0; ++kb)
    attn_iter(kb, L, kBase, vBase, qv, oacc, lacc);

  // ---- combine 4 key-quarter waves + epilogue
  float lfin = lacc + __shfl_xor(lacc, 32, 64);

  #pragma unroll
  for (int pq = 0; pq < 4; ++pq) {
    __syncthreads();
    if (pq == 0 && lo) sm.lsum[ks][l31] = lfin;
    if (ks == pq) {
      #pragma unroll
      for (int ct = 0; ct < 8; ++ct) {
        #pragma unroll
        for (int i = 0; i < 16; ++i) {
          int ch = ct * 32 + (i & 3) + 8 * (i >> 2) + 4 * l5;
          if (pq == 0) sm.obuf[ch][l31] = oacc[ct][i];
          else         sm.obuf[ch][l31] += oacc[ct][i];
        }
      }
    }
  }
  __syncthreads();

  const int row = tid & 31;
  const float coef = gamma[0] / (sm.lsum[0][row] + sm.lsum[1][row] +
                                 sm.lsum[2][row] + sm.lsum[3][row]);
  #pragma unroll 4
  for (int t = 0; t < 32; ++t) {
    int ch = (tid >> 5) + t * 8;
    size_t off = ((size_t)(b * Cn + ch)) * Nn + n0 + row;
    out[off] = sm.obuf[ch][row] * coef + 2.0f * x[off];
  }
}

extern "C" void kernel_launch(void* const* d_in, const int* in_sizes, int n_in,
                              void* d_out, int out_size, void* d_ws, size_t ws_size,
                              hipStream_t stream) {
  const float* x     = (const float*)d_in[0];
  const float* Wq    = (const float*)d_in[1];
  const float* bq    = (const float*)d_in[2];
  const float* Wk    = (const float*)d_in[3];
  const float* bk    = (const float*)d_in[4];
  const float* Wv    = (const float*)d_in[5];
  const float* bv    = (const float*)d_in[6];
  const float* gamma = (const float*)d_in[7];
  float* out = (float*)d_out;

  uint8_t* qF = (uint8_t*)d_ws;                       // 2 MB fp8 x64-frag-major
  uint8_t* kF = qF + (2u << 20);                      // 2 MB
  uint8_t* vF = kF + (2u << 20);                      // 4 MB
  unsigned short* wbf = (unsigned short*)(vF + (4u << 20));  // 256 KB bf16 frag-major

  hipLaunchKernelGGL(cvt_weights, dim3(64), dim3(256), 0, stream, Wq, Wk, Wv, wbf);
  hipLaunchKernelGGL(proj_kernel, dim3(128, 4), dim3(256), 0, stream,
                     x, wbf, bq, bk, bv, qF, kF, vF);
  hipLaunchKernelGGL(attn_kernel, dim3(512), dim3(256), 0, stream,
                     qF, kF, vF, x, gamma, out);
}

// Round 15
// 128.352 us; speedup vs baseline: 1.6335x; 1.0091x over previous
//
#include <hip/hip_runtime.h>
#include <stdint.h>

// BasicAttention: B=4, C=256, IC=128, N=4096, fp32 in/out.
// R22 = FINAL: exact R18 (best verified, 129.3us total / attn 46.8us),
// restoring the compact masked-rotation body (R21's two-segment linearization
// was neutral on total and showed a worse profiled tail -- 2x unrolled body).
// Session ledger: 140.7 -> 129.3us. Wins: fp8 frag pipeline + direct per-reg
// V loads (R11, -11us), MX-scaled x64 MFMA (R12, -4.4us: QK 4 + PV 8 MFMAs
// per 64 keys at 2.14x rate), VALU micros (R10: exp2-fold -> bare v_exp_f32,
// permlane32_swap P-exchange, in-place exp), per-block key-phase rotation
// (R18, -1.7us). Structural limit (written, measured): 128-elem fp32 acc +
// ~128 VGPRs saturate the unified 256-reg file -> hard 2 waves/SIMD; serial
// K->QK->exp->PV chain leaves ~35% SIMD idle that 2 waves can't cover. Six
// structural variants failed (R8 fences, R9 cross-iter compute, R13/R17/R19
// spills, R20 glds-LDS); spill law: any 32-reg live range crossing the loop
// backedge spills. Smaller acc tiles add +50% QK work +8% L2 -- net loss.
// No pipe saturated: register-file-imposed latency floor. Non-attn 83us is
// proj-small + fixed harness overhead, insensitive to all proj variants.
// ws: qF 2MB | kF 2MB | vF 4MB | wbf(bf16) 256KB.

#define Bn 4
#define Cn 256
#define ICn 128
#define Nn 4096

typedef __attribute__((ext_vector_type(8))) short bf16x8;
typedef __attribute__((ext_vector_type(4))) float f32x4;
typedef __attribute__((ext_vector_type(16))) float f32x16;
typedef __attribute__((ext_vector_type(8))) int i32x8;

#define SCALE1 0x7f7f7f7f  // e8m0 127 (=2^0) in all 4 bytes: scale = 1.0

__device__ __forceinline__ unsigned short f2bf(float f) {
  union { float f; uint32_t u; } v; v.f = f;
  uint32_t r = (v.u + 0x7fffu + ((v.u >> 16) & 1u)) >> 16;
  return (unsigned short)r;
}

__device__ __forceinline__ uint32_t pk4_fp8(float a, float b, float c, float d) {
  int r = 0;
  r = __builtin_amdgcn_cvt_pk_fp8_f32(a, b, r, false);
  r = __builtin_amdgcn_cvt_pk_fp8_f32(c, d, r, true);
  return (uint32_t)r;
}

// wbf frag-major (bf16): [tile(32)][kk(8)][lane(64)][j(8)]; tiles 0-7 Wq, 8-15 Wk, 16-31 Wv.
__global__ __launch_bounds__(256) void cvt_weights(const float* __restrict__ Wq,
                                                   const float* __restrict__ Wk,
                                                   const float* __restrict__ Wv,
                                                   unsigned short* __restrict__ wbf) {
  int t = blockIdx.x * 256 + threadIdx.x;   // 0..16383 = tile*512 + kk*64 + lane
  int tile = t >> 9;
  int kk = (t >> 6) & 7;
  int lane = t & 63;
  const float* W; int row;
  if (tile < 8)       { W = Wq; row = tile * 16 + (lane & 15); }
  else if (tile < 16) { W = Wk; row = (tile - 8) * 16 + (lane & 15); }
  else                { W = Wv; row = (tile - 16) * 16 + (lane & 15); }
  const float* src = W + (size_t)row * Cn + kk * 32 + (lane >> 4) * 8;
  float4 f0 = *(const float4*)src;
  float4 f1 = *(const float4*)(src + 4);
  ushort4 o0, o1;
  o0.x = f2bf(f0.x); o0.y = f2bf(f0.y); o0.z = f2bf(f0.z); o0.w = f2bf(f0.w);
  o1.x = f2bf(f1.x); o1.y = f2bf(f1.y); o1.z = f2bf(f1.z); o1.w = f2bf(f1.w);
  *(ushort4*)(wbf + (size_t)t * 8)     = o0;
  *(ushort4*)(wbf + (size_t)t * 8 + 4) = o1;
}

// qF/kF fp8 x64-frag layout: [b][nt(128)][mf(2)][lane(64)][32B]; lane = l5*32+px31,
//   dword d at mf covers ic = mf*64 + l5*32 + d*4 .. +3 for pixel px.
// vF fp8 x64-frag layout: [b][kb64(64)][ct(8)][lane(64)][32B]; lane = l5*32+ch31,
//   dword d covers keys = l5*32 + d*4 .. +3 (within the 64-key block) for ch.
// wave0: q, wave1: k, waves 2-3: v (8 vtg each).
__global__ __launch_bounds__(256, 2) void proj_kernel(const float* __restrict__ x,
                                                      const unsigned short* __restrict__ wbf,
                                                      const float* __restrict__ bq,
                                                      const float* __restrict__ bk,
                                                      const float* __restrict__ bv,
                                                      uint8_t* __restrict__ qF,
                                                      uint8_t* __restrict__ kF,
                                                      uint8_t* __restrict__ vF) {
  const int b = blockIdx.y;
  const int ntile = blockIdx.x;            // 32-pixel tile
  const int px0 = ntile * 32;
  const int tid = threadIdx.x;
  const int lane = tid & 63;
  const int w = tid >> 6;
  const int c0 = lane & 15, g = lane >> 4;
  // 128^-0.25 * sqrt(log2(e)), folded into BOTH q and k: S comes out in log2
  // domain so attn softmax is a bare v_exp_f32 (2^x).
  const float hscale = 0.3570958292f;

  __shared__ __align__(16) unsigned short xT[32][264];  // [px][c] (16.9 KB)
  __shared__ __align__(16) uint8_t tb[4][4096];         // per-wave store-staging (16 KB)

  #pragma unroll
  for (int t = 0; t < 8; ++t) {            // 8 c-rows x 128B contiguous per wave-instr
    int c = (tid >> 3) + t * 32;
    int i8 = tid & 7;
    float4 f4 = *(const float4*)(x + ((size_t)(b * Cn + c)) * Nn + px0 + i8 * 4);
    xT[i8 * 4 + 0][c] = f2bf(f4.x);
    xT[i8 * 4 + 1][c] = f2bf(f4.y);
    xT[i8 * 4 + 2][c] = f2bf(f4.z);
    xT[i8 * 4 + 3][c] = f2bf(f4.w);
  }
  __syncthreads();

  bf16x8 a[2][8];   // x frags for both 16-px halves
  #pragma unroll
  for (int h = 0; h < 2; ++h)
    #pragma unroll
    for (int kk = 0; kk < 8; ++kk)
      a[h][kk] = *(const bf16x8*)&xT[h * 16 + c0][kk * 32 + g * 8];

  f32x4 zero = {0.f, 0.f, 0.f, 0.f};
  uint8_t* tw = &tb[w][0];

  if (w < 2) {
    // wave0: q (wbf tiles 0-7), wave1: k (tiles 8-15). A = W (m=ic), B = x^T (n=px).
    const int isq = (w == 0);
    const float* bias = isq ? bq : bk;
    uint8_t* dst = isq ? qF : kF;
    #pragma unroll
    for (int otl = 0; otl < 8; ++otl) {
      const int wt = (isq ? 0 : 8) + otl;
      bf16x8 wf[8];
      #pragma unroll
      for (int kk = 0; kk < 8; ++kk)
        wf[kk] = *(const bf16x8*)(wbf + (((size_t)wt * 8 + kk) << 9) + lane * 8);
      float4 bz = *(const float4*)(bias + otl * 16 + g * 4);
      #pragma unroll
      for (int h = 0; h < 2; ++h) {
        f32x4 acc = zero;
        #pragma unroll
        for (int kk = 0; kk < 8; ++kk)
          acc = __builtin_amdgcn_mfma_f32_16x16x32_bf16(wf[kk], a[h][kk], acc, 0, 0, 0);
        // D: row = ic = otl*16 + g*4 + r, col = px = h*16 + c0
        uint32_t d = pk4_fp8((acc[0] + bz.x) * hscale, (acc[1] + bz.y) * hscale,
                             (acc[2] + bz.z) * hscale, (acc[3] + bz.w) * hscale);
        // dword D = ic/4 = otl*4+g in [0,32): mf = D>>4, l5 = (D>>3)&1, d = D&7
        int D = otl * 4 + g;
        int off = ((D >> 4) << 11) + (((((D >> 3) & 1) << 5) + h * 16 + c0) << 5) + ((D & 7) << 2);
        *(uint32_t*)(tw + off) = d;            // ds_write_b32 (cheap scatter)
      }
    }
    // coalesced store-back: flat LDS layout == flat global frag layout
    size_t base = ((size_t)(b * 128 + ntile)) << 12;   // 4096B per (b,ntile)
    #pragma unroll
    for (int r = 0; r < 4; ++r) {
      uint4 v = *(const uint4*)(tw + r * 1024 + lane * 16);
      *(uint4*)(dst + base + r * 1024 + lane * 16) = v;
    }
  } else {
    // waves 2,3: v tiles. A = x (m=px), B = W^T (n=ch).
    #pragma unroll
    for (int oi = 0; oi < 8; ++oi) {
      const int vtg = (w - 2) * 8 + oi;
      bf16x8 wf[8];
      #pragma unroll
      for (int kk = 0; kk < 8; ++kk)
        wf[kk] = *(const bf16x8*)(wbf + (((size_t)(16 + vtg) * 8 + kk) << 9) + lane * 8);
      const float bias = bv[vtg * 16 + c0];
      #pragma unroll
      for (int h = 0; h < 2; ++h) {
        f32x4 acc = zero;
        #pragma unroll
        for (int kk = 0; kk < 8; ++kk)
          acc = __builtin_amdgcn_mfma_f32_16x16x32_bf16(a[h][kk], wf[kk], acc, 0, 0, 0);
        // D: row = key = px0 + h*16 + g*4 + r, col = ch = vtg*16 + c0
        uint32_t d = pk4_fp8(acc[0] + bias, acc[1] + bias, acc[2] + bias, acc[3] + bias);
        // tb: [ct_local(4)][ch31(32)][32B], dword = h*4+g
        int off = (((vtg >> 1) & 3) << 10) + ((((vtg & 1) << 4) + c0) << 5) + ((h * 4 + g) << 2);
        *(uint32_t*)(tw + off) = d;            // ds_write_b32
      }
    }
    // coalesced store-back: 2 rounds x (two 1KB segments per wave-instr)
    const int ctb = (w - 2) * 4;
    size_t base0 = (((size_t)(b * 64 + (ntile >> 1)) * 8 + ctb) << 11)
                 + (size_t)(((ntile & 1) << 5) << 5);      // lane-half select
    #pragma unroll
    for (int r = 0; r < 2; ++r) {
      int ctl = r * 2 + (lane >> 5);
      int li = lane & 31;
      const uint8_t* s = tw + r * 2048 + lane * 32;
      uint4 v0 = *(const uint4*)(s);
      uint4 v1 = *(const uint4*)(s + 16);
      uint8_t* gp = vF + base0 + ((size_t)ctl << 11) + li * 32;
      *(uint4*)(gp) = v0;
      *(uint4*)(gp + 16) = v1;
    }
  }
}

// attn: 512 blocks x 256 thr (4 waves = 4 key-quarters), 32 q-rows/block,
// 16 iters x 64 keys, all-MX x64 MFMAs. R12 body + phase rotation (R18).
__global__ __launch_bounds__(256, 2) void attn_kernel(const uint8_t* __restrict__ qF,
                                                      const uint8_t* __restrict__ kF,
                                                      const uint8_t* __restrict__ vF,
                                                      const float* __restrict__ x,
                                                      const float* __restrict__ gamma,
                                                      float* __restrict__ out) {
  const int blk = blockIdx.x;
  const int b = (blk & 7) >> 1;                     // 2 XCDs/batch: q+k+v 2MB < 4MB L2
  const int rg = (blk >> 3) | ((blk & 1) << 6);     // 0..127
  const int n0 = rg * 32;
  const int ph = (blk >> 3) & 15;                   // per-block key-loop phase:
  const int tid = threadIdx.x;                      // co-resident blocks (same blk&7)
  const int L = tid & 63;                           // spread bursts over 16 phases
  const int ks = tid >> 6;                          // key quarter
  const int l31 = L & 31, l5 = L >> 5;
  const bool lo = (l5 == 0);

  __shared__ __align__(16) struct SM {
    float obuf[256][33];                            // epilogue O^T combine (33.8 KB)
    float lsum[4][32];
  } sm;

  // Q B-frags (persistent): col = qrow = n0 + l31; qv[mf] = ic mf*64 + l5*32 + 0..31
  i32x8 qv[2];
  {
    const uint8_t* qp = qF + ((size_t)(b * 128 + rg) * 2) * 2048 + L * 32;
    #pragma unroll
    for (int mf = 0; mf < 2; ++mf) {
      union { uint4 u[2]; i32x8 v; } u;
      u.u[0] = *(const uint4*)(qp + mf * 2048);
      u.u[1] = *(const uint4*)(qp + mf * 2048 + 16);
      qv[mf] = u.v;
    }
  }

  f32x16 oacc[8];                                   // O^T: 256 ch x 32 qrows
  #pragma unroll
  for (int ct = 0; ct < 8; ++ct)
    #pragma unroll
    for (int i = 0; i < 16; ++i) oacc[ct][i] = 0.f;
  float lacc = 0.f;

  const uint8_t* kBase = kF + ((size_t)(b * 128) * 2) * 2048 + L * 32;
  const uint8_t* vBase = vF + ((size_t)(b * 64) * 8) * 2048 + L * 32;

  for (int it = 0; it < 16; ++it) {
    const int kb = ks * 16 + ((it + ph) & 15);      // rotated 64-key block (sum commutes)

    // (1) K frags JIT, issued FIRST: QK's vmcnt wait retires these while the
    //     later-issued V loads stay in flight (in-order retirement).
    i32x8 kv[4];                                    // [tile*2 + mf]
    {
      const uint8_t* kp = kBase + (size_t)kb * 8192;
      #pragma unroll
      for (int f = 0; f < 4; ++f) {
        union { uint4 u[2]; i32x8 v; } u;
        u.u[0] = *(const uint4*)(kp + f * 2048);
        u.u[1] = *(const uint4*)(kp + f * 2048 + 16);
        kv[f] = u.v;
      }
    }

    // (2) V dword-half A (keys l5*32 + 0..15 of each ct); half B issued mid-iter
    //     to cap live VGPRs.
    const uint8_t* vp = vBase + (size_t)kb * 16384;
    uint4 vA[8], vB[8];
    #pragma unroll
    for (int ct = 0; ct < 8; ++ct) vA[ct] = *(const uint4*)(vp + ct * 2048);

    // (3) QK tile1 (keys 0-31), K=128 via 2 x64 steps. S^T: col=l31=qrow,
    //     row(reg i) = key = (i&3)+8*(i>>2)+4*l5.
    f32x16 s;
    #pragma unroll
    for (int i = 0; i < 16; ++i) s[i] = 0.f;
    s = __builtin_amdgcn_mfma_scale_f32_32x32x64_f8f6f4(kv[0], qv[0], s, 0, 0, 0, SCALE1, 0, SCALE1);
    s = __builtin_amdgcn_mfma_scale_f32_32x32x64_f8f6f4(kv[1], qv[1], s, 0, 0, 0, SCALE1, 0, SCALE1);
    // exp/pack tile1 (one S tile live at a time; VGPR cap)
    #pragma unroll
    for (int i = 0; i < 16; ++i) {
      float r;
      asm("v_exp_f32 %0, %1" : "=v"(r) : "v"(s[i]));
      s[i] = r;
    }
    #pragma unroll
    for (int i = 0; i < 16; ++i) lacc += s[i];
    uint32_t d0 = pk4_fp8(s[0], s[1], s[2], s[3]);      // keys lo:0-3  hi:4-7
    uint32_t d1 = pk4_fp8(s[4], s[5], s[6], s[7]);      // keys lo:8-11 hi:12-15
    uint32_t d2 = pk4_fp8(s[8], s[9], s[10], s[11]);    // keys lo:16-19 hi:20-23
    uint32_t d3 = pk4_fp8(s[12], s[13], s[14], s[15]);  // keys lo:24-27 hi:28-31

    // (4) QK tile2 (keys 32-63)
    #pragma unroll
    for (int i = 0; i < 16; ++i) s[i] = 0.f;
    s = __builtin_amdgcn_mfma_scale_f32_32x32x64_f8f6f4(kv[2], qv[0], s, 0, 0, 0, SCALE1, 0, SCALE1);
    s = __builtin_amdgcn_mfma_scale_f32_32x32x64_f8f6f4(kv[3], qv[1], s, 0, 0, 0, SCALE1, 0, SCALE1);

    // (5) V dword-half B issue (covered by exp-t2 + swaps + PV front)
    #pragma unroll
    for (int ct = 0; ct < 8; ++ct) vB[ct] = *(const uint4*)(vp + ct * 2048 + 16);

    #pragma unroll
    for (int i = 0; i < 16; ++i) {
      float r;
      asm("v_exp_f32 %0, %1" : "=v"(r) : "v"(s[i]));
      s[i] = r;
    }
    #pragma unroll
    for (int i = 0; i < 16; ++i) lacc += s[i];
    uint32_t e0 = pk4_fp8(s[0], s[1], s[2], s[3]);
    uint32_t e1 = pk4_fp8(s[4], s[5], s[6], s[7]);
    uint32_t e2 = pk4_fp8(s[8], s[9], s[10], s[11]);
    uint32_t e3 = pk4_fp8(s[12], s[13], s[14], s[15]);

    // (6) P^T B-frag (K=64): swap(a=e_i, b=d_i) -> lane<32: a=partner d_i, b=own d_i;
    //     lane>=32: a=own e_i, b=partner e_i. K order = w[2i]=b_i, w[2i+1]=a_i
    //     (lo lanes keys 0-31 = tile1, hi lanes keys 32-63 = tile2). No selects.
    union { uint32_t w[8]; i32x8 v; } pf;
    {
      uint32_t a0 = e0, b0 = d0;
      asm("v_permlane32_swap_b32 %0, %1" : "+v"(a0), "+v"(b0));
      pf.w[0] = b0; pf.w[1] = a0;
      uint32_t a1 = e1, b1 = d1;
      asm("v_permlane32_swap_b32 %0, %1" : "+v"(a1), "+v"(b1));
      pf.w[2] = b1; pf.w[3] = a1;
      uint32_t a2 = e2, b2 = d2;
      asm("v_permlane32_swap_b32 %0, %1" : "+v"(a2), "+v"(b2));
      pf.w[4] = b2; pf.w[5] = a2;
      uint32_t a3 = e3, b3 = d3;
      asm("v_permlane32_swap_b32 %0, %1" : "+v"(a3), "+v"(b3));
      pf.w[6] = b3; pf.w[7] = a3;
    }

    // (7) O^T += V·P^T: 8 x64 MFMAs. D layout fixed -> epilogue unchanged.
    #pragma unroll
    for (int ct = 0; ct < 8; ++ct) {
      union { uint4 u[2]; i32x8 v; } va;
      va.u[0] = vA[ct]; va.u[1] = vB[ct];
      oacc[ct] = __builtin_amdgcn_mfma_scale_f32_32x32x64_f8f6f4(va.v, pf.v, oacc[ct], 0, 0, 0, SCALE1, 0, SCALE1);
    }
  }

  // ---- combine 4 key-quarter waves + epilogue
  float lfin = lacc + __shfl_xor(lacc, 32, 64);

  #pragma unroll
  for (int pq = 0; pq < 4; ++pq) {
    __syncthreads();
    if (pq == 0 && lo) sm.lsum[ks][l31] = lfin;
    if (ks == pq) {
      #pragma unroll
      for (int ct = 0; ct < 8; ++ct) {
        #pragma unroll
        for (int i = 0; i < 16; ++i) {
          int ch = ct * 32 + (i & 3) + 8 * (i >> 2) + 4 * l5;
          if (pq == 0) sm.obuf[ch][l31] = oacc[ct][i];
          else         sm.obuf[ch][l31] += oacc[ct][i];
        }
      }
    }
  }
  __syncthreads();

  const int row = tid & 31;
  const float coef = gamma[0] / (sm.lsum[0][row] + sm.lsum[1][row] +
                                 sm.lsum[2][row] + sm.lsum[3][row]);
  #pragma unroll 4
  for (int t = 0; t < 32; ++t) {
    int ch = (tid >> 5) + t * 8;
    size_t off = ((size_t)(b * Cn + ch)) * Nn + n0 + row;
    out[off] = sm.obuf[ch][row] * coef + 2.0f * x[off];
  }
}

extern "C" void kernel_launch(void* const* d_in, const int* in_sizes, int n_in,
                              void* d_out, int out_size, void* d_ws, size_t ws_size,
                              hipStream_t stream) {
  const float* x     = (const float*)d_in[0];
  const float* Wq    = (const float*)d_in[1];
  const float* bq    = (const float*)d_in[2];
  const float* Wk    = (const float*)d_in[3];
  const float* bk    = (const float*)d_in[4];
  const float* Wv    = (const float*)d_in[5];
  const float* bv    = (const float*)d_in[6];
  const float* gamma = (const float*)d_in[7];
  float* out = (float*)d_out;

  uint8_t* qF = (uint8_t*)d_ws;                       // 2 MB fp8 x64-frag-major
  uint8_t* kF = qF + (2u << 20);                      // 2 MB
  uint8_t* vF = kF + (2u << 20);                      // 4 MB
  unsigned short* wbf = (unsigned short*)(vF + (4u << 20));  // 256 KB bf16 frag-major

  hipLaunchKernelGGL(cvt_weights, dim3(64), dim3(256), 0, stream, Wq, Wk, Wv, wbf);
  hipLaunchKernelGGL(proj_kernel, dim3(128, 4), dim3(256), 0, stream,
                     x, wbf, bq, bk, bv, qF, kF, vF);
  hipLaunchKernelGGL(attn_kernel, dim3(512), dim3(256), 0, stream,
                     qF, kF, vF, x, gamma, out);
}